// Round 1
// baseline (1020.274 us; speedup 1.0000x reference)
//
#include <hip/hip_runtime.h>
#include <hip/hip_bf16.h>
#include <stdint.h>

// SigLipAttention: B=32,S=576,D=768,H=12,HD=64. Outputs: out[B,S,D] f32, attn[B,H,S,S] f32.
// All matmuls in bf16 MFMA (16x16x32), f32 accumulate. SCALE=1/8 folded into Q (exact).

#define BATCH 32
#define SEQ   576
#define DMODEL 768
#define NHEAD 12
#define HDIM  64

typedef unsigned short u16;
typedef short bf16x8 __attribute__((ext_vector_type(8)));
typedef float f32x4 __attribute__((ext_vector_type(4)));

__device__ __forceinline__ u16 f2bf(float f) {
  uint32_t u = __float_as_uint(f);
  u += 0x7fffu + ((u >> 16) & 1u);   // RNE
  return (u16)(u >> 16);
}
__device__ __forceinline__ float bf2f(u16 b) {
  return __uint_as_float(((uint32_t)b) << 16);
}

// ---------------- cast f32 -> bf16, 4 elems/thread ----------------
__global__ __launch_bounds__(256) void cast_bf16(const float* __restrict__ in,
                                                 u16* __restrict__ out, int n4) {
  int i = blockIdx.x * 256 + threadIdx.x;
  if (i < n4) {
    float4 v = ((const float4*)in)[i];
    u16 o0 = f2bf(v.x), o1 = f2bf(v.y), o2 = f2bf(v.z), o3 = f2bf(v.w);
    uint32_t lo = (uint32_t)o0 | ((uint32_t)o1 << 16);
    uint32_t hi = (uint32_t)o2 | ((uint32_t)o3 << 16);
    ((uint2*)out)[i] = make_uint2(lo, hi);
  }
}

// ---------------- GEMM: C[m][n] = alpha*(sum_k A[m][k]*B[n][k] + bias[n]) ----------------
// A: [M][K] bf16 row-major, B: [N][K] bf16 row-major (i.e. torch W layout), both K-contiguous.
// 128x128 tile, BK=32, 4 waves (2x2), each wave 64x64 = 4x4 frags of 16x16x32.
template<int OUT_BF16>
__global__ __launch_bounds__(256) void gemm_bt(
    const u16* __restrict__ A, const u16* __restrict__ B,
    const float* __restrict__ bias, float alpha, void* __restrict__ Cout,
    int M, int N, int K) {
  __shared__ u16 As[128 * 32];
  __shared__ u16 Bs[128 * 32];
  const int tid = threadIdx.x;
  const int wave = tid >> 6, lane = tid & 63;
  const int wm = (wave >> 1) * 64, wn = (wave & 1) * 64;
  const int bm = blockIdx.x, bn = blockIdx.y;
  const u16* Ab = A + (size_t)bm * 128 * K;
  const u16* Bb = B + (size_t)bn * 128 * K;
  f32x4 acc[4][4] = {};
  const int r0 = tid >> 2;            // staging row (0..63), +64 for j=1
  const int c0 = (tid & 3) * 8;       // staging col group
  const int lr = lane & 15, lk = (lane >> 4) * 8;

  for (int kt = 0; kt < K; kt += 32) {
    __syncthreads();                  // previous compute done before overwrite
#pragma unroll
    for (int j = 0; j < 2; ++j) {
      __builtin_amdgcn_global_load_lds(
          (const __attribute__((address_space(1))) void*)(Ab + (size_t)(r0 + j * 64) * K + kt + c0),
          (__attribute__((address_space(3))) void*)(As + (j * 256 + wave * 64) * 8),
          16, 0, 0);
    }
#pragma unroll
    for (int j = 0; j < 2; ++j) {
      __builtin_amdgcn_global_load_lds(
          (const __attribute__((address_space(1))) void*)(Bb + (size_t)(r0 + j * 64) * K + kt + c0),
          (__attribute__((address_space(3))) void*)(Bs + (j * 256 + wave * 64) * 8),
          16, 0, 0);
    }
    __syncthreads();                  // drains vmcnt before barrier (compiler-enforced)

    bf16x8 af[4], bfr[4];
#pragma unroll
    for (int i = 0; i < 4; ++i) {
      af[i]  = *(const bf16x8*)(As + (wm + i * 16 + lr) * 32 + lk);
      bfr[i] = *(const bf16x8*)(Bs + (wn + i * 16 + lr) * 32 + lk);
    }
#pragma unroll
    for (int i = 0; i < 4; ++i)
#pragma unroll
      for (int j = 0; j < 4; ++j)
        acc[i][j] = __builtin_amdgcn_mfma_f32_16x16x32_bf16(af[i], bfr[j], acc[i][j], 0, 0, 0);
  }

  // epilogue: D frag mapping col=lane&15, row=(lane>>4)*4+r
#pragma unroll
  for (int j = 0; j < 4; ++j) {
    const int col = bn * 128 + wn + j * 16 + lr;
    const float bv = bias[col];
#pragma unroll
    for (int i = 0; i < 4; ++i) {
      const int rowb = bm * 128 + wm + i * 16 + (lane >> 4) * 4;
#pragma unroll
      for (int r = 0; r < 4; ++r) {
        const float v = alpha * (acc[i][j][r] + bv);
        if (OUT_BF16)
          ((u16*)Cout)[(size_t)(rowb + r) * N + col] = f2bf(v);
        else
          ((float*)Cout)[(size_t)(rowb + r) * N + col] = v;
      }
    }
  }
}

// ---------------- fused attention ----------------
// grid (S/32, H, B), 256 threads. Per block: 32 q-rows of one (b,h).
// Phase1: S=Q*K^T (scale pre-folded in Q) -> bf16 scores in LDS.
// Phase2: row softmax (8 lanes/row); writes attn f32 to d_out; unnormalized P bf16 in LDS.
// Phase3: O = P*V via MFMA (V transposed through LDS in 64-chunks); 1/sum in epilogue.
__global__ __launch_bounds__(256) void attn_fused(
    const u16* __restrict__ Q, const u16* __restrict__ K,
    const u16* __restrict__ V, float* __restrict__ attn_out,
    u16* __restrict__ O) {
  __shared__ u16 P_lds[32][584];   // +8 pad: ds_read_b128 lanes land on distinct banks
  __shared__ u16 Vt[64][72];       // V chunk transposed [hd][s], +8 pad
  __shared__ float row_inv[32];
  const int qt = blockIdx.x, h = blockIdx.y, b = blockIdx.z;
  const int tid = threadIdx.x, wave = tid >> 6, lane = tid & 63;
  const int q0 = qt * 32;
  const size_t base = (size_t)b * SEQ * DMODEL + h * HDIM;
  const int lr = lane & 15, lk = (lane >> 4) * 8;

  // ---- Phase 1: scores ----
  bf16x8 aq[2][2];
#pragma unroll
  for (int mf = 0; mf < 2; ++mf)
#pragma unroll
    for (int ks = 0; ks < 2; ++ks)
      aq[mf][ks] = *(const bf16x8*)(Q + base + (size_t)(q0 + mf * 16 + lr) * DMODEL + ks * 32 + lk);

  const int n0w = wave * 144;      // each wave owns 144 key-cols
  for (int nf = 0; nf < 9; ++nf) {
    const int n0 = n0w + nf * 16;
    bf16x8 bk[2];
#pragma unroll
    for (int ks = 0; ks < 2; ++ks)
      bk[ks] = *(const bf16x8*)(K + base + (size_t)(n0 + lr) * DMODEL + ks * 32 + lk);
    f32x4 accs[2] = {};
#pragma unroll
    for (int mf = 0; mf < 2; ++mf)
#pragma unroll
      for (int ks = 0; ks < 2; ++ks)
        accs[mf] = __builtin_amdgcn_mfma_f32_16x16x32_bf16(aq[mf][ks], bk[ks], accs[mf], 0, 0, 0);
#pragma unroll
    for (int mf = 0; mf < 2; ++mf)
#pragma unroll
      for (int r = 0; r < 4; ++r)
        P_lds[mf * 16 + (lane >> 4) * 4 + r][n0 + lr] = f2bf(accs[mf][r]);
  }
  __syncthreads();

  // ---- Phase 2: softmax, 8 lanes per row, contiguous 72-col segments ----
  {
    const int row = tid >> 3, rl = tid & 7;
    const int cb = rl * 72;
    float m = -1e30f;
    for (int i = 0; i < 72; ++i) m = fmaxf(m, bf2f(P_lds[row][cb + i]));
#pragma unroll
    for (int off = 1; off < 8; off <<= 1) m = fmaxf(m, __shfl_xor(m, off));
    float sum = 0.f;
    for (int i = 0; i < 72; ++i) {
      float e = __expf(bf2f(P_lds[row][cb + i]) - m);
      sum += e;
      P_lds[row][cb + i] = f2bf(e);   // unnormalized P
    }
#pragma unroll
    for (int off = 1; off < 8; off <<= 1) sum += __shfl_xor(sum, off);
    const float inv = 1.f / sum;
    if (rl == 0) row_inv[row] = inv;
    float* arow = attn_out + (((size_t)b * NHEAD + h) * SEQ + (q0 + row)) * SEQ + cb;
    for (int i = 0; i < 72; i += 4) {
      float4 o4;
      o4.x = bf2f(P_lds[row][cb + i + 0]) * inv;
      o4.y = bf2f(P_lds[row][cb + i + 1]) * inv;
      o4.z = bf2f(P_lds[row][cb + i + 2]) * inv;
      o4.w = bf2f(P_lds[row][cb + i + 3]) * inv;
      *(float4*)(arow + i) = o4;
    }
  }

  // ---- Phase 3: O = P * V ----
  f32x4 accO[2] = {};
  const int mf3 = wave >> 1;           // wave's m-frag (0..1)
  const int nb3 = (wave & 1) * 2;      // wave's 2 n-frags
  for (int ch = 0; ch < 9; ++ch) {
    __syncthreads();                   // P writes visible / prev chunk consumed
    const int s0 = ch * 64;
#pragma unroll
    for (int j = 0; j < 2; ++j) {
      const int idx = j * 256 + tid;
      const int r = idx >> 3, cv = (idx & 7) * 8;
      bf16x8 vv = *(const bf16x8*)(V + base + (size_t)(s0 + r) * DMODEL + cv);
#pragma unroll
      for (int i = 0; i < 8; ++i) Vt[cv + i][r] = (u16)vv[i];
    }
    __syncthreads();
#pragma unroll
    for (int ks = 0; ks < 2; ++ks) {
      bf16x8 ap = *(const bf16x8*)(&P_lds[mf3 * 16 + lr][s0 + ks * 32 + lk]);
#pragma unroll
      for (int nn = 0; nn < 2; ++nn) {
        bf16x8 bv = *(const bf16x8*)(&Vt[(nb3 + nn) * 16 + lr][ks * 32 + lk]);
        accO[nn] = __builtin_amdgcn_mfma_f32_16x16x32_bf16(ap, bv, accO[nn], 0, 0, 0);
      }
    }
  }
#pragma unroll
  for (int nn = 0; nn < 2; ++nn) {
    const int col = (nb3 + nn) * 16 + lr;
#pragma unroll
    for (int r = 0; r < 4; ++r) {
      const int row = mf3 * 16 + (lane >> 4) * 4 + r;
      O[base + (size_t)(q0 + row) * DMODEL + col] = f2bf(accO[nn][r] * row_inv[row]);
    }
  }
}

extern "C" void kernel_launch(void* const* d_in, const int* in_sizes, int n_in,
                              void* d_out, int out_size, void* d_ws, size_t ws_size,
                              hipStream_t stream) {
  const float* hs = (const float*)d_in[0];
  const float* Wq = (const float*)d_in[1];
  const float* bq = (const float*)d_in[2];
  const float* Wk = (const float*)d_in[3];
  const float* bk = (const float*)d_in[4];
  const float* Wv = (const float*)d_in[5];
  const float* bv = (const float*)d_in[6];
  const float* Wo = (const float*)d_in[7];
  const float* bo = (const float*)d_in[8];
  float* out  = (float*)d_out;
  float* attn = out + (size_t)BATCH * SEQ * DMODEL;

  const size_t nTok  = (size_t)BATCH * SEQ;     // 18432
  const size_t szHid = nTok * DMODEL;           // 14,155,776
  const size_t szW   = (size_t)DMODEL * DMODEL; // 589,824

  u16* hidb = (u16*)d_ws;                 // also reused as O (alias; hidden dead by then)
  u16* wqb  = hidb + szHid;
  u16* wkb  = wqb + szW;
  u16* wvb  = wkb + szW;
  u16* wob  = wvb + szW;
  u16* Qb   = wob + szW;
  u16* Kb   = Qb + szHid;
  u16* Vb   = Kb + szHid;
  u16* Ob   = hidb;

  const int n4h = (int)(szHid / 4);
  const int n4w = (int)(szW / 4);
  cast_bf16<<<dim3((n4h + 255) / 256), 256, 0, stream>>>(hs, hidb, n4h);
  cast_bf16<<<dim3((n4w + 255) / 256), 256, 0, stream>>>(Wq, wqb, n4w);
  cast_bf16<<<dim3((n4w + 255) / 256), 256, 0, stream>>>(Wk, wkb, n4w);
  cast_bf16<<<dim3((n4w + 255) / 256), 256, 0, stream>>>(Wv, wvb, n4w);
  cast_bf16<<<dim3((n4w + 255) / 256), 256, 0, stream>>>(Wo, wob, n4w);

  dim3 gproj(144, 6);  // M/128, N/128
  gemm_bt<1><<<gproj, 256, 0, stream>>>(hidb, wqb, bq, 0.125f, Qb, 18432, DMODEL, DMODEL);
  gemm_bt<1><<<gproj, 256, 0, stream>>>(hidb, wkb, bk, 1.0f,   Kb, 18432, DMODEL, DMODEL);
  gemm_bt<1><<<gproj, 256, 0, stream>>>(hidb, wvb, bv, 1.0f,   Vb, 18432, DMODEL, DMODEL);

  attn_fused<<<dim3(SEQ / 32, NHEAD, BATCH), 256, 0, stream>>>(Qb, Kb, Vb, attn, Ob);

  gemm_bt<0><<<gproj, 256, 0, stream>>>(Ob, wob, bo, 1.0f, out, 18432, DMODEL, DMODEL);
}